// Round 14
// baseline (24.300 us; speedup 1.0000x reference)
//
#include <hip/hip_runtime.h>
#include <math.h>

// SegmentTreeAttention — MI355X (gfx950), round 14.
// B=16, S=8192, D=64, N=32, LEVELS=5. f32 in/out. valid_lens per-batch.
//
// r13 (coef-folded gather) = 23.9us best. This round: three safe
// micro-cuts, no new state, cond logic bit-identical:
//  1. n==0 early-out (block-uniform): output is exactly 0 -> write and
//     return (1/32 of batches skip everything).
//  2. rcl identity (n>=1): okL = cm>=l, okR = rcl>=mid+1 with
//     rcl = cond?cm:rcl (init hnc). Removes 2 mins/level/query + r var.
//  3. wsel = RCPF(max(dnL,dnR)) == cond?dnR:dnL -- v_max off the cond
//     chain; differs only ~1ulp in the rescued-gray corner (output-only).
// Keeps: QPB=64, 2-query ILP, DPP reduce, clamp identity, div-free cond
// + gray rescue, pow2 scales, coef-folded gather, byte offsets, q-hoist.

#define SEG_N   32
#define DIM     64
#define LEVELS  5
#define QPB     64      // queries per block
#define THREADS 256
#define PAD     68      // LDS row stride in dwords
#define PADB    (PAD * 4)

#define DPP_QUAD_XOR1   0xB1    // quad_perm [1,0,3,2]
#define DPP_QUAD_XOR2   0x4E    // quad_perm [2,3,0,1]
#define DPP_ROW_HMIRROR 0x141   // row_half_mirror (lane p -> 7-p within 8)

#if __has_builtin(__builtin_amdgcn_rcpf)
#define RCPF(x) __builtin_amdgcn_rcpf(x)
#else
#define RCPF(x) (1.0f / (x))
#endif

template <int CTRL>
__device__ __forceinline__ float dpp_xadd(float v) {
    const int s = __builtin_amdgcn_update_dpp(0, __float_as_int(v), CTRL, 0xf, 0xf, true);
    return v + __int_as_float(s);
}

// 8-lane group sum, all lanes get the bit-identical total.
__device__ __forceinline__ float group8_sum(float v) {
    v = dpp_xadd<DPP_QUAD_XOR1>(v);
    v = dpp_xadd<DPP_QUAD_XOR2>(v);
    v = dpp_xadd<DPP_ROW_HMIRROR>(v);
    return v;
}

__device__ __forceinline__ float4 f4sub(const float4 a, const float4 b) {
    return make_float4(a.x - b.x, a.y - b.y, a.z - b.z, a.w - b.w);
}
__device__ __forceinline__ float dot4(const float4 a, const float4 b) {
    return a.x * b.x + a.y * b.y + a.z * b.z + a.w * b.w;
}
// acc += v * w
__device__ __forceinline__ void fmaw(float4& acc, const float4 v, float w) {
    acc.x = fmaf(v.x, w, acc.x);
    acc.y = fmaf(v.y, w, acc.y);
    acc.z = fmaf(v.z, w, acc.z);
    acc.w = fmaf(v.w, w, acc.w);
}

__global__ __launch_bounds__(THREADS) void segtree_attn_kernel(
    const float* __restrict__ q,
    const float* __restrict__ keys,
    const float* __restrict__ values,
    const int*   __restrict__ vlen,
    float*       __restrict__ out,
    int S)
{
    __shared__ float P[2][SEG_N * PAD];   // P[0]=Pk, P[1]=Pv

    const int b = blockIdx.y;
    const int t = threadIdx.x;
    const int g = t >> 3;           // query group within block (0..31)
    const int u = t & 7;            // lane within group
    const int c = u * 8;            // column base (2x float4)
    const int c4 = c * 4;           // byte offset of column base

    const int sA = blockIdx.x * QPB + g;
    const int sB = sA + 32;
    float* opA = out + ((size_t)b * S + sA) * DIM + c;
    float* opB = out + ((size_t)b * S + sB) * DIM + c;

    const int n = vlen[b];          // block-uniform (valid_lens is [B])

    // ---- n==0: every segment is masked -> output exactly zero ----
    if (n == 0) {
        const float4 z = make_float4(0.f, 0.f, 0.f, 0.f);
        *(float4*)opA       = z;
        *(float4*)(opA + 4) = z;
        *(float4*)opB       = z;
        *(float4*)(opB + 4) = z;
        return;
    }

    // ---- q loads hoisted: latency hides under staging + barrier ----
    const float* qpA = q + ((size_t)b * S + sA) * DIM + c;
    const float* qpB = q + ((size_t)b * S + sB) * DIM + c;
    const float4 qA0 = *(const float4*)qpA;
    const float4 qA1 = *(const float4*)(qpA + 4);
    const float4 qB0 = *(const float4*)qpB;
    const float4 qB1 = *(const float4*)(qpB + 4);

    // ---- Stage prefix sums into LDS: P[0]=0, P[m]=sum_{l=1..m} x[l] ----
    if (t < 2 * DIM) {
        const int col = t & (DIM - 1);
        const float* src = ((t < DIM) ? keys : values) + (size_t)b * SEG_N * DIM + col;
        float* dst = (t < DIM) ? P[0] : P[1];
        float acc = 0.0f;
        dst[col] = 0.0f;
        #pragma unroll
        for (int row = 1; row < SEG_N; ++row) {
            acc += src[row * DIM];
            dst[row * PAD + col] = acc;
        }
    }
    __syncthreads();

    const int hnc = n - 1 < SEG_N - 1 ? n - 1 : SEG_N - 1;   // n>=1 here
    const float scale[LEVELS] = {0.0625f, 0.125f, 0.25f, 0.5f, 1.0f};
    const char* Kb = (const char*)&P[0][0];
    const char* Vb = (const char*)&P[1][0];

    // initial frontiers: P[l-1]=P[0]=0 ; P[clamp(min(r,n-1))] = P[hnc]
    const int offN = hnc * PADB + c4;
    float4 pkR_A0 = *(const float4*)(Kb + offN);
    float4 pkR_A1 = *(const float4*)(Kb + offN + 16);
    float4 pkR_B0 = pkR_A0, pkR_B1 = pkR_A1;
    float4 pkA_A0 = make_float4(0.f,0.f,0.f,0.f), pkA_A1 = make_float4(0.f,0.f,0.f,0.f);
    float4 pkA_B0 = make_float4(0.f,0.f,0.f,0.f), pkA_B1 = make_float4(0.f,0.f,0.f,0.f);

    int offA_A = c4, offR_A = offN;     // byte offsets of frontier rows
    int offA_B = c4, offR_B = offN;
    float cA_A = 0.0f, cR_A = 0.0f;     // running coefs of frontier rows
    float cA_B = 0.0f, cR_B = 0.0f;
    int midA = 16, midB = 16;
    int lA = 1, lB = 1;
    int rclA = hnc, rclB = hnc;         // rcl = min(r, n-1), maintained

    // emissions: one finalized (row, coef) per level + 2 final frontiers
    float cE_A[LEVELS + 2], cE_B[LEVELS + 2];
    int   rowE_A[LEVELS + 2], rowE_B[LEVELS + 2];

    #pragma unroll
    for (int lev = 0; lev < LEVELS; ++lev) {
        const int step = 8 >> lev;
        const int cmA = midA < hnc ? midA : hnc;   // clamped row
        const int cmB = midB < hnc ? midB : hnc;
        const int offMA = cmA * PADB + c4;
        const int offMB = cmB * PADB + c4;

        const float4 pkM_A0 = *(const float4*)(Kb + offMA);
        const float4 pkM_A1 = *(const float4*)(Kb + offMA + 16);
        const float4 pkM_B0 = *(const float4*)(Kb + offMB);
        const float4 pkM_B1 = *(const float4*)(Kb + offMB + 16);

        // subtract-then-dot (matches reference rounding structure)
        float dLA = dot4(qA0, f4sub(pkM_A0, pkA_A0)) + dot4(qA1, f4sub(pkM_A1, pkA_A1));
        float dRA = dot4(qA0, f4sub(pkR_A0, pkM_A0)) + dot4(qA1, f4sub(pkR_A1, pkM_A1));
        float dLB = dot4(qB0, f4sub(pkM_B0, pkA_B0)) + dot4(qB1, f4sub(pkM_B1, pkA_B1));
        float dRB = dot4(qB0, f4sub(pkR_B0, pkM_B0)) + dot4(qB1, f4sub(pkR_B1, pkM_B1));

        dLA = group8_sum(dLA);
        dRA = group8_sum(dRA);
        dLB = group8_sum(dLB);
        dRB = group8_sum(dRB);

        // ok via rcl identity (exact for n>=1)
        const bool okLA = (cmA >= lA);
        const bool okRA = (rclA >= midA + 1);
        const bool okLB = (cmB >= lB);
        const bool okRB = (rclB >= midB + 1);

        const float sLA = okLA ? dLA : 0.0f;
        const float sRA = okRA ? dRA : 0.0f;
        const float sLB = okLB ? dLB : 0.0f;
        const float sRB = okRB ? dRB : 0.0f;

        // sigmoid denominators (exact, same __expf as all passing rounds)
        const float dnLA = 1.0f + __expf(-sLA);
        const float dnRA = 1.0f + __expf(-sRA);
        const float dnLB = 1.0f + __expf(-sLB);
        const float dnRB = 1.0f + __expf(-sRB);

        // div-free cond with gray rescue (r10-validated, bit-exact)
        bool condA = (dnLA <= dnRA);
        bool condB = (dnLB <= dnRB);
        const bool grayA = (dnLA > dnRA) && ((dnLA - dnRA) < dnLA * 1e-6f);
        const bool grayB = (dnLB > dnRB) && ((dnLB - dnRB) < dnLB * 1e-6f);
        if (__any(grayA || grayB)) {        // P ~ 1e-5 per wave-level
            condA = ((1.0f / dnLA) >= (1.0f / dnRA));
            condB = ((1.0f / dnLB) >= (1.0f / dnRB));
        }

        // wsel = cond?dnR:dnL == max(dnL,dnR) (off the cond chain;
        // ~1ulp weight shift only in the rescued-gray corner)
        const float wselA = RCPF(fmaxf(dnLA, dnRA));
        const float wselB = RCPF(fmaxf(dnLB, dnRB));
        const bool  okselA = condA ? okRA : okLA;
        const bool  okselB = condB ? okRB : okLB;
        const float wAv = okselA ? (wselA * scale[lev]) : 0.0f;  // pow2: exact
        const float wBv = okselB ? (wselB * scale[lev]) : 0.0f;

        // ---- coefficient-folded emission (static slot = lev) ----
        rowE_A[lev] = condA ? offR_A : offA_A;
        cE_A[lev]   = condA ? (cR_A + wAv) : (cA_A - wAv);
        rowE_B[lev] = condB ? offR_B : offA_B;
        cE_B[lev]   = condB ? (cR_B + wBv) : (cA_B - wBv);

        cR_A   = condA ? -wAv  : cR_A;
        cA_A   = condA ? cA_A  : wAv;
        offR_A = condA ? offMA : offR_A;
        offA_A = condA ? offA_A : offMA;
        rclA   = condA ? cmA   : rclA;
        cR_B   = condB ? -wBv  : cR_B;
        cA_B   = condB ? cA_B  : wBv;
        offR_B = condB ? offMB : offR_B;
        offA_B = condB ? offA_B : offMB;
        rclB   = condB ? cmB   : rclB;

        if (condA) {
            pkR_A0 = pkM_A0; pkR_A1 = pkM_A1;
        } else {
            lA = midA + 1;
            pkA_A0 = pkM_A0; pkA_A1 = pkM_A1;
        }
        if (condB) {
            pkR_B0 = pkM_B0; pkR_B1 = pkM_B1;
        } else {
            lB = midB + 1;
            pkA_B0 = pkM_B0; pkA_B1 = pkM_B1;
        }
        if (lev < LEVELS - 1) {
            midA = condA ? (midA - step) : (midA + step);
            midB = condB ? (midB - step) : (midB + step);
        }
    }

    // final frontier emissions
    rowE_A[LEVELS]     = offA_A;  cE_A[LEVELS]     = cA_A;
    rowE_A[LEVELS + 1] = offR_A;  cE_A[LEVELS + 1] = cR_A;
    rowE_B[LEVELS]     = offA_B;  cE_B[LEVELS]     = cA_B;
    rowE_B[LEVELS + 1] = offR_B;  cE_B[LEVELS + 1] = cR_B;

    // ---- folded gather: ans = sum_e coef_e * Pv[row_e]  (7 rows) ----
    float4 aA0 = make_float4(0.f,0.f,0.f,0.f), aA1 = make_float4(0.f,0.f,0.f,0.f);
    float4 aB0 = make_float4(0.f,0.f,0.f,0.f), aB1 = make_float4(0.f,0.f,0.f,0.f);
    #pragma unroll
    for (int e = 0; e < LEVELS + 2; ++e) {
        const float4 vA0 = *(const float4*)(Vb + rowE_A[e]);
        const float4 vA1 = *(const float4*)(Vb + rowE_A[e] + 16);
        fmaw(aA0, vA0, cE_A[e]);
        fmaw(aA1, vA1, cE_A[e]);
        const float4 vB0 = *(const float4*)(Vb + rowE_B[e]);
        const float4 vB1 = *(const float4*)(Vb + rowE_B[e] + 16);
        fmaw(aB0, vB0, cE_B[e]);
        fmaw(aB1, vB1, cE_B[e]);
    }

    *(float4*)opA       = aA0;
    *(float4*)(opA + 4) = aA1;
    *(float4*)opB       = aB0;
    *(float4*)(opB + 4) = aB1;
}

extern "C" void kernel_launch(void* const* d_in, const int* in_sizes, int n_in,
                              void* d_out, int out_size, void* d_ws, size_t ws_size,
                              hipStream_t stream) {
    const float* q    = (const float*)d_in[0];
    const float* keys = (const float*)d_in[1];
    const float* vals = (const float*)d_in[2];
    const int*   vl   = (const int*)d_in[3];
    float* out = (float*)d_out;

    const int B = in_sizes[3];                 // 16
    const int S = in_sizes[0] / (B * DIM);     // 8192

    dim3 grid(S / QPB, B);
    segtree_attn_kernel<<<grid, THREADS, 0, stream>>>(q, keys, vals, vl, out, S);
}

// Round 15
// 24.011 us; speedup vs baseline: 1.0120x; 1.0120x over previous
//
#include <hip/hip_runtime.h>
#include <math.h>

// SegmentTreeAttention — MI355X (gfx950), round 15.
// B=16, S=8192, D=64, N=32, LEVELS=5. f32 in/out. valid_lens per-batch.
//
// r14 micro-cuts were noise -> reverted to r13 (23.9us best).
// This round: QPB=128 via an unrolled it-loop x2 over the r13 descent
// (r2-proven pattern). Grid 2048 -> 1024 blocks: halves total staging
// work (each block re-derives the same 16KB prefix tables) and launch
// overhead at constant descent math and ~constant VGPR (state reused
// across iterations). r8 showed the symmetric move (QPB 64->32) cost
// +1.5us in staging redundancy; this reclaims that coin.
// Descent body is r13 VERBATIM: DPP reduce, clamp identity, div-free
// cond + gray rescue (bit-exact), rcp weights, coef-folded gather.

#define SEG_N   32
#define DIM     64
#define LEVELS  5
#define QPB     128     // queries per block (2 it-loop passes of 64)
#define THREADS 256
#define PAD     68      // LDS row stride in dwords
#define PADB    (PAD * 4)

#define DPP_QUAD_XOR1   0xB1    // quad_perm [1,0,3,2]
#define DPP_QUAD_XOR2   0x4E    // quad_perm [2,3,0,1]
#define DPP_ROW_HMIRROR 0x141   // row_half_mirror (lane p -> 7-p within 8)

#if __has_builtin(__builtin_amdgcn_rcpf)
#define RCPF(x) __builtin_amdgcn_rcpf(x)
#else
#define RCPF(x) (1.0f / (x))
#endif

template <int CTRL>
__device__ __forceinline__ float dpp_xadd(float v) {
    const int s = __builtin_amdgcn_update_dpp(0, __float_as_int(v), CTRL, 0xf, 0xf, true);
    return v + __int_as_float(s);
}

// 8-lane group sum, all lanes get the bit-identical total.
__device__ __forceinline__ float group8_sum(float v) {
    v = dpp_xadd<DPP_QUAD_XOR1>(v);
    v = dpp_xadd<DPP_QUAD_XOR2>(v);
    v = dpp_xadd<DPP_ROW_HMIRROR>(v);
    return v;
}

__device__ __forceinline__ float4 f4sub(const float4 a, const float4 b) {
    return make_float4(a.x - b.x, a.y - b.y, a.z - b.z, a.w - b.w);
}
__device__ __forceinline__ float dot4(const float4 a, const float4 b) {
    return a.x * b.x + a.y * b.y + a.z * b.z + a.w * b.w;
}
// acc += v * w
__device__ __forceinline__ void fmaw(float4& acc, const float4 v, float w) {
    acc.x = fmaf(v.x, w, acc.x);
    acc.y = fmaf(v.y, w, acc.y);
    acc.z = fmaf(v.z, w, acc.z);
    acc.w = fmaf(v.w, w, acc.w);
}

__global__ __launch_bounds__(THREADS) void segtree_attn_kernel(
    const float* __restrict__ q,
    const float* __restrict__ keys,
    const float* __restrict__ values,
    const int*   __restrict__ vlen,
    float*       __restrict__ out,
    int S)
{
    __shared__ float P[2][SEG_N * PAD];   // P[0]=Pk, P[1]=Pv

    const int b = blockIdx.y;
    const int t = threadIdx.x;
    const int g = t >> 3;           // query group within block (0..31)
    const int u = t & 7;            // lane within group
    const int c = u * 8;            // column base (2x float4)
    const int c4 = c * 4;           // byte offset of column base

    // ---- Stage prefix sums into LDS: P[0]=0, P[m]=sum_{l=1..m} x[l] ----
    if (t < 2 * DIM) {
        const int col = t & (DIM - 1);
        const float* src = ((t < DIM) ? keys : values) + (size_t)b * SEG_N * DIM + col;
        float* dst = (t < DIM) ? P[0] : P[1];
        float acc = 0.0f;
        dst[col] = 0.0f;
        #pragma unroll
        for (int row = 1; row < SEG_N; ++row) {
            acc += src[row * DIM];
            dst[row * PAD + col] = acc;
        }
    }
    const int n = vlen[b];          // block-uniform (valid_lens is [B])
    __syncthreads();

    const int hnc = max(min(n - 1, SEG_N - 1), 0);
    const float scale[LEVELS] = {0.0625f, 0.125f, 0.25f, 0.5f, 1.0f};
    const char* Kb = (const char*)&P[0][0];
    const char* Vb = (const char*)&P[1][0];
    const int offN = hnc * PADB + c4;
    const float4 pkN0 = *(const float4*)(Kb + offN);
    const float4 pkN1 = *(const float4*)(Kb + offN + 16);

    #pragma unroll
    for (int it = 0; it < 2; ++it) {
        const int sA = blockIdx.x * QPB + it * 64 + g;
        const int sB = sA + 32;

        const float* qpA = q + ((size_t)b * S + sA) * DIM + c;
        const float* qpB = q + ((size_t)b * S + sB) * DIM + c;
        const float4 qA0 = *(const float4*)qpA;
        const float4 qA1 = *(const float4*)(qpA + 4);
        const float4 qB0 = *(const float4*)qpB;
        const float4 qB1 = *(const float4*)(qpB + 4);

        // initial frontiers: P[l-1]=P[0]=0 ; P[clamp(min(r,n-1))]=P[hnc]
        float4 pkR_A0 = pkN0, pkR_A1 = pkN1;
        float4 pkR_B0 = pkN0, pkR_B1 = pkN1;
        float4 pkA_A0 = make_float4(0.f,0.f,0.f,0.f), pkA_A1 = make_float4(0.f,0.f,0.f,0.f);
        float4 pkA_B0 = make_float4(0.f,0.f,0.f,0.f), pkA_B1 = make_float4(0.f,0.f,0.f,0.f);

        int offA_A = c4, offR_A = offN;     // byte offsets of frontier rows
        int offA_B = c4, offR_B = offN;
        float cA_A = 0.0f, cR_A = 0.0f;     // running coefs of frontier rows
        float cA_B = 0.0f, cR_B = 0.0f;
        int midA = 16, midB = 16;
        int lA = 1, rA = SEG_N;
        int lB = 1, rB = SEG_N;

        // emissions: one finalized (row, coef) per level + 2 final frontiers
        float cE_A[LEVELS + 2], cE_B[LEVELS + 2];
        int   rowE_A[LEVELS + 2], rowE_B[LEVELS + 2];

        #pragma unroll
        for (int lev = 0; lev < LEVELS; ++lev) {
            const int step = 8 >> lev;
            const int cmA = min(midA, hnc);     // clamped row (clamp identity)
            const int cmB = min(midB, hnc);
            const int offMA = cmA * PADB + c4;
            const int offMB = cmB * PADB + c4;

            const float4 pkM_A0 = *(const float4*)(Kb + offMA);
            const float4 pkM_A1 = *(const float4*)(Kb + offMA + 16);
            const float4 pkM_B0 = *(const float4*)(Kb + offMB);
            const float4 pkM_B1 = *(const float4*)(Kb + offMB + 16);

            // subtract-then-dot (matches reference rounding structure)
            float dLA = dot4(qA0, f4sub(pkM_A0, pkA_A0)) + dot4(qA1, f4sub(pkM_A1, pkA_A1));
            float dRA = dot4(qA0, f4sub(pkR_A0, pkM_A0)) + dot4(qA1, f4sub(pkR_A1, pkM_A1));
            float dLB = dot4(qB0, f4sub(pkM_B0, pkA_B0)) + dot4(qB1, f4sub(pkM_B1, pkA_B1));
            float dRB = dot4(qB0, f4sub(pkR_B0, pkM_B0)) + dot4(qB1, f4sub(pkR_B1, pkM_B1));

            dLA = group8_sum(dLA);
            dRA = group8_sum(dRA);
            dLB = group8_sum(dLB);
            dRB = group8_sum(dRB);

            const bool okLA = (min(midA, n - 1) >= lA);
            const bool okRA = (min(rA,   n - 1) >= midA + 1);
            const bool okLB = (min(midB, n - 1) >= lB);
            const bool okRB = (min(rB,   n - 1) >= midB + 1);

            const float sLA = okLA ? dLA : 0.0f;
            const float sRA = okRA ? dRA : 0.0f;
            const float sLB = okLB ? dLB : 0.0f;
            const float sRB = okRB ? dRB : 0.0f;

            // sigmoid denominators (exact, same __expf as all passing rounds)
            const float dnLA = 1.0f + __expf(-sLA);
            const float dnRA = 1.0f + __expf(-sRA);
            const float dnLB = 1.0f + __expf(-sLB);
            const float dnRB = 1.0f + __expf(-sRB);

            // div-free cond with gray rescue (r10-validated, bit-exact)
            bool condA = (dnLA <= dnRA);
            bool condB = (dnLB <= dnRB);
            const bool grayA = (dnLA > dnRA) && ((dnLA - dnRA) < dnLA * 1e-6f);
            const bool grayB = (dnLB > dnRB) && ((dnLB - dnRB) < dnLB * 1e-6f);
            if (__any(grayA || grayB)) {        // P ~ 1e-5 per wave-level
                condA = ((1.0f / dnLA) >= (1.0f / dnRA));
                condB = ((1.0f / dnLB) >= (1.0f / dnRB));
            }

            const bool  okselA = condA ? okRA : okLA;
            const bool  okselB = condB ? okRB : okLB;
            const float wselA  = RCPF(condA ? dnRA : dnLA);  // weight: <=1ulp
            const float wselB  = RCPF(condB ? dnRB : dnLB);
            const float wAv = okselA ? (wselA * scale[lev]) : 0.0f;  // pow2: exact
            const float wBv = okselB ? (wselB * scale[lev]) : 0.0f;

            // ---- coefficient-folded emission (static slot = lev) ----
            rowE_A[lev] = condA ? offR_A : offA_A;
            cE_A[lev]   = condA ? (cR_A + wAv) : (cA_A - wAv);
            rowE_B[lev] = condB ? offR_B : offA_B;
            cE_B[lev]   = condB ? (cR_B + wBv) : (cA_B - wBv);

            cR_A   = condA ? -wAv  : cR_A;
            cA_A   = condA ? cA_A  : wAv;
            offR_A = condA ? offMA : offR_A;
            offA_A = condA ? offA_A : offMA;
            cR_B   = condB ? -wBv  : cR_B;
            cA_B   = condB ? cA_B  : wBv;
            offR_B = condB ? offMB : offR_B;
            offA_B = condB ? offA_B : offMB;

            if (condA) {
                rA = midA;
                pkR_A0 = pkM_A0; pkR_A1 = pkM_A1;
            } else {
                lA = midA + 1;
                pkA_A0 = pkM_A0; pkA_A1 = pkM_A1;
            }
            if (condB) {
                rB = midB;
                pkR_B0 = pkM_B0; pkR_B1 = pkM_B1;
            } else {
                lB = midB + 1;
                pkA_B0 = pkM_B0; pkA_B1 = pkM_B1;
            }
            if (lev < LEVELS - 1) {
                midA = condA ? (midA - step) : (midA + step);
                midB = condB ? (midB - step) : (midB + step);
            }
        }

        // final frontier emissions
        rowE_A[LEVELS]     = offA_A;  cE_A[LEVELS]     = cA_A;
        rowE_A[LEVELS + 1] = offR_A;  cE_A[LEVELS + 1] = cR_A;
        rowE_B[LEVELS]     = offA_B;  cE_B[LEVELS]     = cA_B;
        rowE_B[LEVELS + 1] = offR_B;  cE_B[LEVELS + 1] = cR_B;

        // ---- folded gather: ans = sum_e coef_e * Pv[row_e]  (7 rows) ----
        float4 aA0 = make_float4(0.f,0.f,0.f,0.f), aA1 = make_float4(0.f,0.f,0.f,0.f);
        float4 aB0 = make_float4(0.f,0.f,0.f,0.f), aB1 = make_float4(0.f,0.f,0.f,0.f);
        #pragma unroll
        for (int e = 0; e < LEVELS + 2; ++e) {
            const float4 vA0 = *(const float4*)(Vb + rowE_A[e]);
            const float4 vA1 = *(const float4*)(Vb + rowE_A[e] + 16);
            fmaw(aA0, vA0, cE_A[e]);
            fmaw(aA1, vA1, cE_A[e]);
            const float4 vB0 = *(const float4*)(Vb + rowE_B[e]);
            const float4 vB1 = *(const float4*)(Vb + rowE_B[e] + 16);
            fmaw(aB0, vB0, cE_B[e]);
            fmaw(aB1, vB1, cE_B[e]);
        }

        float* opA = out + ((size_t)b * S + sA) * DIM + c;
        float* opB = out + ((size_t)b * S + sB) * DIM + c;
        *(float4*)opA       = aA0;
        *(float4*)(opA + 4) = aA1;
        *(float4*)opB       = aB0;
        *(float4*)(opB + 4) = aB1;
    }
}

extern "C" void kernel_launch(void* const* d_in, const int* in_sizes, int n_in,
                              void* d_out, int out_size, void* d_ws, size_t ws_size,
                              hipStream_t stream) {
    const float* q    = (const float*)d_in[0];
    const float* keys = (const float*)d_in[1];
    const float* vals = (const float*)d_in[2];
    const int*   vl   = (const int*)d_in[3];
    float* out = (float*)d_out;

    const int B = in_sizes[3];                 // 16
    const int S = in_sizes[0] / (B * DIM);     // 8192

    dim3 grid(S / QPB, B);
    segtree_attn_kernel<<<grid, THREADS, 0, stream>>>(q, keys, vals, vl, out, S);
}